// Round 1
// baseline (1485.525 us; speedup 1.0000x reference)
//
#include <hip/hip_runtime.h>
#include <hip/hip_bf16.h>
#include <math.h>

#define NE 8
#define MM 2048
#define DH 1024   // hidden
#define DI 4096   // intermediate

#define BK  32
#define LDA 40    // padded LDS row stride (bf16 elems): 40*2=80B -> bank spread

typedef short bf16x8 __attribute__((ext_vector_type(8)));
typedef float f32x4  __attribute__((ext_vector_type(4)));

__device__ __forceinline__ unsigned short f2bf(float f) {
    unsigned u = __builtin_bit_cast(unsigned, f);
    u += 0x7FFFu + ((u >> 16) & 1u);   // round-to-nearest-even
    return (unsigned short)(u >> 16);
}

// ---------------- GEMM1: H = gelu_erf(X @ W1), X fp32 [M,DH], W1 fp32 [DH,DI], H bf16 [M,DI]
__global__ __launch_bounds__(256, 2)
void gemm1_gelu(const float* __restrict__ X, const float* __restrict__ W1,
                unsigned short* __restrict__ H)
{
    __shared__ short As[128 * LDA];
    __shared__ short Bs[128 * LDA];

    const int e  = blockIdx.z;
    const int m0 = blockIdx.y * 128;
    const int n0 = blockIdx.x * 128;

    const float* Xe  = X  + (size_t)e * MM * DH;
    const float* W1e = W1 + (size_t)e * DH * DI;
    unsigned short* He = H + (size_t)e * MM * DI;

    const int tid  = threadIdx.x;
    const int lane = tid & 63;
    const int wave = tid >> 6;
    const int wm = (wave >> 1) * 64;
    const int wn = (wave &  1) * 64;
    const int lr = lane & 15;   // row (A) / col (B) within 16
    const int lq = lane >> 4;   // k-quad

    f32x4 acc[4][4] = {};

    for (int k0 = 0; k0 < DH; k0 += BK) {
        // stage A: 128 rows x 32 k (fp32 -> bf16)
        #pragma unroll
        for (int i = 0; i < 4; ++i) {
            int idx = tid + i * 256;          // float4 index 0..1023
            int row = idx >> 3;               // 8 float4 per row
            int col = (idx & 7) * 4;
            const float4 v = *(const float4*)(Xe + (size_t)(m0 + row) * DH + k0 + col);
            short4 s;
            s.x = (short)f2bf(v.x); s.y = (short)f2bf(v.y);
            s.z = (short)f2bf(v.z); s.w = (short)f2bf(v.w);
            *(short4*)(&As[row * LDA + col]) = s;
        }
        // stage B: 32 k-rows x 128 n (fp32), transpose into Bs[n][k]
        #pragma unroll
        for (int i = 0; i < 4; ++i) {
            int idx  = tid + i * 256;
            int krow = idx >> 5;              // 32 float4 per k-row
            int ncol = (idx & 31) * 4;
            const float4 v = *(const float4*)(W1e + (size_t)(k0 + krow) * DI + n0 + ncol);
            Bs[(ncol + 0) * LDA + krow] = (short)f2bf(v.x);
            Bs[(ncol + 1) * LDA + krow] = (short)f2bf(v.y);
            Bs[(ncol + 2) * LDA + krow] = (short)f2bf(v.z);
            Bs[(ncol + 3) * LDA + krow] = (short)f2bf(v.w);
        }
        __syncthreads();

        bf16x8 a[4], b[4];
        #pragma unroll
        for (int i = 0; i < 4; ++i)
            a[i] = *(const bf16x8*)(&As[(wm + i * 16 + lr) * LDA + lq * 8]);
        #pragma unroll
        for (int i = 0; i < 4; ++i)
            b[i] = *(const bf16x8*)(&Bs[(wn + i * 16 + lr) * LDA + lq * 8]);
        #pragma unroll
        for (int mi = 0; mi < 4; ++mi)
            #pragma unroll
            for (int ni = 0; ni < 4; ++ni)
                acc[mi][ni] = __builtin_amdgcn_mfma_f32_16x16x32_bf16(a[mi], b[ni], acc[mi][ni], 0, 0, 0);
        __syncthreads();
    }

    // epilogue: exact-erf GELU, store bf16
    #pragma unroll
    for (int mi = 0; mi < 4; ++mi) {
        #pragma unroll
        for (int ni = 0; ni < 4; ++ni) {
            const int col = n0 + wn + ni * 16 + lr;
            #pragma unroll
            for (int r = 0; r < 4; ++r) {
                const int row = m0 + wm + mi * 16 + lq * 4 + r;
                float v = acc[mi][ni][r];
                float g = 0.5f * v * (1.0f + erff(v * 0.70710678118654752f));
                He[(size_t)row * DI + col] = f2bf(g);
            }
        }
    }
}

// ---------------- GEMM2: O = H @ W2, H bf16 [M,DI], W2 fp32 [DI,DH], O fp32 [M,DH]
__global__ __launch_bounds__(256, 2)
void gemm2(const unsigned short* __restrict__ H, const float* __restrict__ W2,
           float* __restrict__ O)
{
    __shared__ short As[128 * LDA];
    __shared__ short Bs[128 * LDA];

    const int e  = blockIdx.z;
    const int m0 = blockIdx.y * 128;
    const int n0 = blockIdx.x * 128;

    const unsigned short* He = H + (size_t)e * MM * DI;
    const float* W2e = W2 + (size_t)e * DI * DH;
    float* Oe = O + (size_t)e * MM * DH;

    const int tid  = threadIdx.x;
    const int lane = tid & 63;
    const int wave = tid >> 6;
    const int wm = (wave >> 1) * 64;
    const int wn = (wave &  1) * 64;
    const int lr = lane & 15;
    const int lq = lane >> 4;

    f32x4 acc[4][4] = {};

    for (int k0 = 0; k0 < DI; k0 += BK) {
        // stage A: 128 rows x 32 k, already bf16 -> 16B vector copies
        #pragma unroll
        for (int i = 0; i < 2; ++i) {
            int idx = tid + i * 256;          // short8 index 0..511
            int row = idx >> 2;               // 4 short8 per row
            int col = (idx & 3) * 8;
            bf16x8 v = *(const bf16x8*)(He + (size_t)(m0 + row) * DI + k0 + col);
            *(bf16x8*)(&As[row * LDA + col]) = v;
        }
        // stage B: 32 k-rows x 128 n of W2 (fp32), transpose into Bs[n][k]
        #pragma unroll
        for (int i = 0; i < 4; ++i) {
            int idx  = tid + i * 256;
            int krow = idx >> 5;
            int ncol = (idx & 31) * 4;
            const float4 v = *(const float4*)(W2e + (size_t)(k0 + krow) * DH + n0 + ncol);
            Bs[(ncol + 0) * LDA + krow] = (short)f2bf(v.x);
            Bs[(ncol + 1) * LDA + krow] = (short)f2bf(v.y);
            Bs[(ncol + 2) * LDA + krow] = (short)f2bf(v.z);
            Bs[(ncol + 3) * LDA + krow] = (short)f2bf(v.w);
        }
        __syncthreads();

        bf16x8 a[4], b[4];
        #pragma unroll
        for (int i = 0; i < 4; ++i)
            a[i] = *(const bf16x8*)(&As[(wm + i * 16 + lr) * LDA + lq * 8]);
        #pragma unroll
        for (int i = 0; i < 4; ++i)
            b[i] = *(const bf16x8*)(&Bs[(wn + i * 16 + lr) * LDA + lq * 8]);
        #pragma unroll
        for (int mi = 0; mi < 4; ++mi)
            #pragma unroll
            for (int ni = 0; ni < 4; ++ni)
                acc[mi][ni] = __builtin_amdgcn_mfma_f32_16x16x32_bf16(a[mi], b[ni], acc[mi][ni], 0, 0, 0);
        __syncthreads();
    }

    #pragma unroll
    for (int mi = 0; mi < 4; ++mi) {
        #pragma unroll
        for (int ni = 0; ni < 4; ++ni) {
            const int col = n0 + wn + ni * 16 + lr;
            #pragma unroll
            for (int r = 0; r < 4; ++r) {
                const int row = m0 + wm + mi * 16 + lq * 4 + r;
                Oe[(size_t)row * DH + col] = acc[mi][ni][r];
            }
        }
    }
}

extern "C" void kernel_launch(void* const* d_in, const int* in_sizes, int n_in,
                              void* d_out, int out_size, void* d_ws, size_t ws_size,
                              hipStream_t stream) {
    const float* x  = (const float*)d_in[0];
    const float* w1 = (const float*)d_in[1];
    const float* w2 = (const float*)d_in[2];
    float* out = (float*)d_out;
    // hidden intermediate (bf16): 8*2048*4096*2 = 128 MB in workspace
    unsigned short* hidden = (unsigned short*)d_ws;

    dim3 blk(256);
    gemm1_gelu<<<dim3(DI / 128, MM / 128, NE), blk, 0, stream>>>(x, w1, hidden);
    gemm2    <<<dim3(DH / 128, MM / 128, NE), blk, 0, stream>>>(hidden, w2, out);
}

// Round 2
// 755.605 us; speedup vs baseline: 1.9660x; 1.9660x over previous
//
#include <hip/hip_runtime.h>
#include <hip/hip_bf16.h>
#include <math.h>

#define NE 8
#define MM 2048
#define DH 1024   // hidden
#define DI 4096   // intermediate

#define BK  32
#define LDA 40    // padded LDS stride for manually-staged tiles

typedef short bf16x8 __attribute__((ext_vector_type(8)));
typedef float f32x4  __attribute__((ext_vector_type(4)));

__device__ __forceinline__ unsigned short f2bf(float f) {
    unsigned u = __builtin_bit_cast(unsigned, f);
    u += 0x7FFFu + ((u >> 16) & 1u);   // round-to-nearest-even
    return (unsigned short)(u >> 16);
}

// async global(16B/lane) -> LDS. lds ptr must be wave-uniform base; HW adds lane*16.
__device__ __forceinline__ void gload_lds16(const void* g, void* l) {
    __builtin_amdgcn_global_load_lds(
        (__attribute__((address_space(1))) void*)g,
        (__attribute__((address_space(3))) void*)l, 16, 0, 0);
}

// ---------------- weight transpose+convert: fp32 [K,N] -> bf16 [N,K], per expert
__global__ __launch_bounds__(256)
void transpose_bf16(const float* __restrict__ in, unsigned short* __restrict__ out,
                    int K, int N)
{
    __shared__ short tile[64][66];   // 66-short stride: bank stride 33 -> conflict-free-ish
    const int e  = blockIdx.z;
    const int n0 = blockIdx.x * 64;
    const int k0 = blockIdx.y * 64;
    const float* ine = in + (size_t)e * K * N;
    unsigned short* oute = out + (size_t)e * N * K;
    const int tid = threadIdx.x;

    #pragma unroll
    for (int i = 0; i < 4; ++i) {
        int idx = tid + i * 256;          // float4 index over 64x16
        int r  = idx >> 4;
        int c  = (idx & 15) * 4;
        const float4 v = *(const float4*)(ine + (size_t)(k0 + r) * N + n0 + c);
        tile[r][c + 0] = (short)f2bf(v.x);
        tile[r][c + 1] = (short)f2bf(v.y);
        tile[r][c + 2] = (short)f2bf(v.z);
        tile[r][c + 3] = (short)f2bf(v.w);
    }
    __syncthreads();
    #pragma unroll
    for (int i = 0; i < 4; ++i) {
        int idx = tid + i * 256;          // short4 index over 64x16
        int n  = idx >> 4;
        int k  = (idx & 15) * 4;
        short4 s;
        s.x = tile[k + 0][n];
        s.y = tile[k + 1][n];
        s.z = tile[k + 2][n];
        s.w = tile[k + 3][n];
        *(short4*)(oute + (size_t)(n0 + n) * K + k0 + k) = s;
    }
}

// ---------------- GEMM1: H = gelu_erf(X @ W1), X fp32 [M,DH], W1t bf16 [DI,DH], H bf16 [M,DI]
__global__ __launch_bounds__(256, 2)
void gemm1_gelu(const float* __restrict__ X, const unsigned short* __restrict__ W1t,
                unsigned short* __restrict__ H)
{
    __shared__ short As[128 * LDA];    // padded (manual stage)
    __shared__ short Bs[128 * 32];     // UNPADDED (global_load_lds layout)

    const int e  = blockIdx.z;
    const int m0 = blockIdx.y * 128;
    const int n0 = blockIdx.x * 128;

    const float* Xe = X + (size_t)e * MM * DH;
    const unsigned short* Bt = W1t + (size_t)e * DI * DH;
    unsigned short* He = H + (size_t)e * MM * DI;

    const int tid  = threadIdx.x;
    const int lane = tid & 63;
    const int wave = tid >> 6;
    const int wm = (wave >> 1) * 64;
    const int wn = (wave &  1) * 64;
    const int lr = lane & 15;
    const int lq = lane >> 4;

    f32x4 acc[4][4] = {};

    for (int k0 = 0; k0 < DH; k0 += BK) {
        // B: async bf16 stage, 128x32 = 8KB -> 2 issues of 256 lanes x 16B
        #pragma unroll
        for (int i = 0; i < 2; ++i) {
            int idx  = tid + i * 256;              // 16B-chunk id
            int row  = idx >> 2;
            int col  = (idx & 3) * 8;
            gload_lds16(Bt + (size_t)(n0 + row) * DH + k0 + col,
                        Bs + (i * 256 + wave * 64) * 8);
        }
        // A: fp32 load + convert (padded LDS)
        #pragma unroll
        for (int i = 0; i < 4; ++i) {
            int idx = tid + i * 256;
            int row = idx >> 3;
            int col = (idx & 7) * 4;
            const float4 v = *(const float4*)(Xe + (size_t)(m0 + row) * DH + k0 + col);
            short4 s;
            s.x = (short)f2bf(v.x); s.y = (short)f2bf(v.y);
            s.z = (short)f2bf(v.z); s.w = (short)f2bf(v.w);
            *(short4*)(&As[row * LDA + col]) = s;
        }
        __syncthreads();

        bf16x8 a[4], b[4];
        #pragma unroll
        for (int i = 0; i < 4; ++i)
            a[i] = *(const bf16x8*)(&As[(wm + i * 16 + lr) * LDA + lq * 8]);
        #pragma unroll
        for (int i = 0; i < 4; ++i)
            b[i] = *(const bf16x8*)(&Bs[(wn + i * 16 + lr) * 32 + lq * 8]);
        #pragma unroll
        for (int mi = 0; mi < 4; ++mi)
            #pragma unroll
            for (int ni = 0; ni < 4; ++ni)
                acc[mi][ni] = __builtin_amdgcn_mfma_f32_16x16x32_bf16(a[mi], b[ni], acc[mi][ni], 0, 0, 0);
        __syncthreads();
    }

    #pragma unroll
    for (int mi = 0; mi < 4; ++mi) {
        #pragma unroll
        for (int ni = 0; ni < 4; ++ni) {
            const int col = n0 + wn + ni * 16 + lr;
            #pragma unroll
            for (int r = 0; r < 4; ++r) {
                const int row = m0 + wm + mi * 16 + lq * 4 + r;
                float v = acc[mi][ni][r];
                float g = 0.5f * v * (1.0f + erff(v * 0.70710678118654752f));
                He[(size_t)row * DI + col] = f2bf(g);
            }
        }
    }
}

// ---------------- GEMM2: O = H @ W2, H bf16 [M,DI], W2t bf16 [DH,DI], O fp32 [M,DH]
__global__ __launch_bounds__(256, 2)
void gemm2(const unsigned short* __restrict__ H, const unsigned short* __restrict__ W2t,
           float* __restrict__ O)
{
    __shared__ short As[128 * 32];     // UNPADDED
    __shared__ short Bs[128 * 32];     // UNPADDED

    const int e  = blockIdx.z;
    const int m0 = blockIdx.y * 128;
    const int n0 = blockIdx.x * 128;

    const unsigned short* He = H + (size_t)e * MM * DI;
    const unsigned short* Bt = W2t + (size_t)e * DH * DI;
    float* Oe = O + (size_t)e * MM * DH;

    const int tid  = threadIdx.x;
    const int lane = tid & 63;
    const int wave = tid >> 6;
    const int wm = (wave >> 1) * 64;
    const int wn = (wave &  1) * 64;
    const int lr = lane & 15;
    const int lq = lane >> 4;

    f32x4 acc[4][4] = {};

    for (int k0 = 0; k0 < DI; k0 += BK) {
        #pragma unroll
        for (int i = 0; i < 2; ++i) {
            int idx = tid + i * 256;
            int row = idx >> 2;
            int col = (idx & 3) * 8;
            gload_lds16(He + (size_t)(m0 + row) * DI + k0 + col,
                        As + (i * 256 + wave * 64) * 8);
            gload_lds16(Bt + (size_t)(n0 + row) * DI + k0 + col,
                        Bs + (i * 256 + wave * 64) * 8);
        }
        __syncthreads();

        bf16x8 a[4], b[4];
        #pragma unroll
        for (int i = 0; i < 4; ++i)
            a[i] = *(const bf16x8*)(&As[(wm + i * 16 + lr) * 32 + lq * 8]);
        #pragma unroll
        for (int i = 0; i < 4; ++i)
            b[i] = *(const bf16x8*)(&Bs[(wn + i * 16 + lr) * 32 + lq * 8]);
        #pragma unroll
        for (int mi = 0; mi < 4; ++mi)
            #pragma unroll
            for (int ni = 0; ni < 4; ++ni)
                acc[mi][ni] = __builtin_amdgcn_mfma_f32_16x16x32_bf16(a[mi], b[ni], acc[mi][ni], 0, 0, 0);
        __syncthreads();
    }

    #pragma unroll
    for (int mi = 0; mi < 4; ++mi) {
        #pragma unroll
        for (int ni = 0; ni < 4; ++ni) {
            const int col = n0 + wn + ni * 16 + lr;
            #pragma unroll
            for (int r = 0; r < 4; ++r) {
                const int row = m0 + wm + mi * 16 + lq * 4 + r;
                Oe[(size_t)row * DH + col] = acc[mi][ni][r];
            }
        }
    }
}

// ================= fallback (round-1, needs only 128MB ws) =================
__global__ __launch_bounds__(256, 2)
void fb_gemm1(const float* __restrict__ X, const float* __restrict__ W1,
              unsigned short* __restrict__ H)
{
    __shared__ short As[128 * LDA];
    __shared__ short Bs[128 * LDA];
    const int e  = blockIdx.z;
    const int m0 = blockIdx.y * 128;
    const int n0 = blockIdx.x * 128;
    const float* Xe  = X  + (size_t)e * MM * DH;
    const float* W1e = W1 + (size_t)e * DH * DI;
    unsigned short* He = H + (size_t)e * MM * DI;
    const int tid  = threadIdx.x;
    const int lane = tid & 63;
    const int wave = tid >> 6;
    const int wm = (wave >> 1) * 64;
    const int wn = (wave &  1) * 64;
    const int lr = lane & 15;
    const int lq = lane >> 4;
    f32x4 acc[4][4] = {};
    for (int k0 = 0; k0 < DH; k0 += BK) {
        #pragma unroll
        for (int i = 0; i < 4; ++i) {
            int idx = tid + i * 256;
            int row = idx >> 3;
            int col = (idx & 7) * 4;
            const float4 v = *(const float4*)(Xe + (size_t)(m0 + row) * DH + k0 + col);
            short4 s;
            s.x = (short)f2bf(v.x); s.y = (short)f2bf(v.y);
            s.z = (short)f2bf(v.z); s.w = (short)f2bf(v.w);
            *(short4*)(&As[row * LDA + col]) = s;
        }
        #pragma unroll
        for (int i = 0; i < 4; ++i) {
            int idx  = tid + i * 256;
            int krow = idx >> 5;
            int ncol = (idx & 31) * 4;
            const float4 v = *(const float4*)(W1e + (size_t)(k0 + krow) * DI + n0 + ncol);
            Bs[(ncol + 0) * LDA + krow] = (short)f2bf(v.x);
            Bs[(ncol + 1) * LDA + krow] = (short)f2bf(v.y);
            Bs[(ncol + 2) * LDA + krow] = (short)f2bf(v.z);
            Bs[(ncol + 3) * LDA + krow] = (short)f2bf(v.w);
        }
        __syncthreads();
        bf16x8 a[4], b[4];
        #pragma unroll
        for (int i = 0; i < 4; ++i)
            a[i] = *(const bf16x8*)(&As[(wm + i * 16 + lr) * LDA + lq * 8]);
        #pragma unroll
        for (int i = 0; i < 4; ++i)
            b[i] = *(const bf16x8*)(&Bs[(wn + i * 16 + lr) * LDA + lq * 8]);
        #pragma unroll
        for (int mi = 0; mi < 4; ++mi)
            #pragma unroll
            for (int ni = 0; ni < 4; ++ni)
                acc[mi][ni] = __builtin_amdgcn_mfma_f32_16x16x32_bf16(a[mi], b[ni], acc[mi][ni], 0, 0, 0);
        __syncthreads();
    }
    #pragma unroll
    for (int mi = 0; mi < 4; ++mi) {
        #pragma unroll
        for (int ni = 0; ni < 4; ++ni) {
            const int col = n0 + wn + ni * 16 + lr;
            #pragma unroll
            for (int r = 0; r < 4; ++r) {
                const int row = m0 + wm + mi * 16 + lq * 4 + r;
                float v = acc[mi][ni][r];
                float g = 0.5f * v * (1.0f + erff(v * 0.70710678118654752f));
                He[(size_t)row * DI + col] = f2bf(g);
            }
        }
    }
}

__global__ __launch_bounds__(256, 2)
void fb_gemm2(const unsigned short* __restrict__ H, const float* __restrict__ W2,
              float* __restrict__ O)
{
    __shared__ short As[128 * LDA];
    __shared__ short Bs[128 * LDA];
    const int e  = blockIdx.z;
    const int m0 = blockIdx.y * 128;
    const int n0 = blockIdx.x * 128;
    const unsigned short* He = H + (size_t)e * MM * DI;
    const float* W2e = W2 + (size_t)e * DI * DH;
    float* Oe = O + (size_t)e * MM * DH;
    const int tid  = threadIdx.x;
    const int lane = tid & 63;
    const int wave = tid >> 6;
    const int wm = (wave >> 1) * 64;
    const int wn = (wave &  1) * 64;
    const int lr = lane & 15;
    const int lq = lane >> 4;
    f32x4 acc[4][4] = {};
    for (int k0 = 0; k0 < DI; k0 += BK) {
        #pragma unroll
        for (int i = 0; i < 2; ++i) {
            int idx = tid + i * 256;
            int row = idx >> 2;
            int col = (idx & 3) * 8;
            bf16x8 v = *(const bf16x8*)(He + (size_t)(m0 + row) * DI + k0 + col);
            *(bf16x8*)(&As[row * LDA + col]) = v;
        }
        #pragma unroll
        for (int i = 0; i < 4; ++i) {
            int idx  = tid + i * 256;
            int krow = idx >> 5;
            int ncol = (idx & 31) * 4;
            const float4 v = *(const float4*)(W2e + (size_t)(k0 + krow) * DH + n0 + ncol);
            Bs[(ncol + 0) * LDA + krow] = (short)f2bf(v.x);
            Bs[(ncol + 1) * LDA + krow] = (short)f2bf(v.y);
            Bs[(ncol + 2) * LDA + krow] = (short)f2bf(v.z);
            Bs[(ncol + 3) * LDA + krow] = (short)f2bf(v.w);
        }
        __syncthreads();
        bf16x8 a[4], b[4];
        #pragma unroll
        for (int i = 0; i < 4; ++i)
            a[i] = *(const bf16x8*)(&As[(wm + i * 16 + lr) * LDA + lq * 8]);
        #pragma unroll
        for (int i = 0; i < 4; ++i)
            b[i] = *(const bf16x8*)(&Bs[(wn + i * 16 + lr) * LDA + lq * 8]);
        #pragma unroll
        for (int mi = 0; mi < 4; ++mi)
            #pragma unroll
            for (int ni = 0; ni < 4; ++ni)
                acc[mi][ni] = __builtin_amdgcn_mfma_f32_16x16x32_bf16(a[mi], b[ni], acc[mi][ni], 0, 0, 0);
        __syncthreads();
    }
    #pragma unroll
    for (int mi = 0; mi < 4; ++mi) {
        #pragma unroll
        for (int ni = 0; ni < 4; ++ni) {
            const int col = n0 + wn + ni * 16 + lr;
            #pragma unroll
            for (int r = 0; r < 4; ++r) {
                const int row = m0 + wm + mi * 16 + lq * 4 + r;
                Oe[(size_t)row * DH + col] = acc[mi][ni][r];
            }
        }
    }
}

extern "C" void kernel_launch(void* const* d_in, const int* in_sizes, int n_in,
                              void* d_out, int out_size, void* d_ws, size_t ws_size,
                              hipStream_t stream) {
    const float* x  = (const float*)d_in[0];
    const float* w1 = (const float*)d_in[1];
    const float* w2 = (const float*)d_in[2];
    float* out = (float*)d_out;

    const size_t WT_BYTES     = (size_t)NE * DH * DI * 2;   // 64 MB (reused for w1t then w2t)
    const size_t HIDDEN_BYTES = (size_t)NE * MM * DI * 2;   // 128 MB

    dim3 blk(256);
    if (ws_size >= WT_BYTES + HIDDEN_BYTES) {
        unsigned short* wt     = (unsigned short*)d_ws;
        unsigned short* hidden = (unsigned short*)((char*)d_ws + WT_BYTES);
        // w1 [DH,DI] -> w1t [DI,DH]
        transpose_bf16<<<dim3(DI / 64, DH / 64, NE), blk, 0, stream>>>(w1, wt, DH, DI);
        gemm1_gelu<<<dim3(DI / 128, MM / 128, NE), blk, 0, stream>>>(x, wt, hidden);
        // w2 [DI,DH] -> w2t [DH,DI]  (overwrites w1t; stream-ordered, safe)
        transpose_bf16<<<dim3(DH / 64, DI / 64, NE), blk, 0, stream>>>(w2, wt, DI, DH);
        gemm2<<<dim3(DH / 128, MM / 128, NE), blk, 0, stream>>>(hidden, wt, out);
    } else {
        unsigned short* hidden = (unsigned short*)d_ws;
        fb_gemm1<<<dim3(DI / 128, MM / 128, NE), blk, 0, stream>>>(x, w1, hidden);
        fb_gemm2<<<dim3(DH / 128, MM / 128, NE), blk, 0, stream>>>(hidden, w2, out);
    }
}

// Round 3
// 721.114 us; speedup vs baseline: 2.0600x; 1.0478x over previous
//
#include <hip/hip_runtime.h>
#include <hip/hip_bf16.h>
#include <math.h>

#define NE 8
#define MM 2048
#define DH 1024   // hidden
#define DI 4096   // intermediate

#define BK  32
#define LDA 40    // padded LDS stride for manually-staged fp32 tiles

typedef short bf16x8 __attribute__((ext_vector_type(8)));
typedef float f32x4  __attribute__((ext_vector_type(4)));

__device__ __forceinline__ unsigned short f2bf(float f) {
    unsigned u = __builtin_bit_cast(unsigned, f);
    u += 0x7FFFu + ((u >> 16) & 1u);   // round-to-nearest-even
    return (unsigned short)(u >> 16);
}

// async global(16B/lane) -> LDS. lds ptr must be wave-uniform base; HW adds lane*16.
__device__ __forceinline__ void gload_lds16(const void* g, void* l) {
    __builtin_amdgcn_global_load_lds(
        (__attribute__((address_space(1))) void*)g,
        (__attribute__((address_space(3))) void*)l, 16, 0, 0);
}

// ---------------- elementwise fp32 -> bf16 (for X)
__global__ __launch_bounds__(256)
void convert_bf16(const float* __restrict__ in, unsigned short* __restrict__ out,
                  long long n)   // n multiple of 8*256
{
    long long i = ((long long)blockIdx.x * 256 + threadIdx.x) * 8;
    const float4 v0 = *(const float4*)(in + i);
    const float4 v1 = *(const float4*)(in + i + 4);
    bf16x8 s;
    s[0] = (short)f2bf(v0.x); s[1] = (short)f2bf(v0.y);
    s[2] = (short)f2bf(v0.z); s[3] = (short)f2bf(v0.w);
    s[4] = (short)f2bf(v1.x); s[5] = (short)f2bf(v1.y);
    s[6] = (short)f2bf(v1.z); s[7] = (short)f2bf(v1.w);
    *(bf16x8*)(out + i) = s;
}

// ---------------- weight transpose+convert: fp32 [K,N] -> bf16 [N,K], per expert
__global__ __launch_bounds__(256)
void transpose_bf16(const float* __restrict__ in, unsigned short* __restrict__ out,
                    int K, int N)
{
    __shared__ short tile[64][66];
    const int e  = blockIdx.z;
    const int n0 = blockIdx.x * 64;
    const int k0 = blockIdx.y * 64;
    const float* ine = in + (size_t)e * K * N;
    unsigned short* oute = out + (size_t)e * N * K;
    const int tid = threadIdx.x;

    #pragma unroll
    for (int i = 0; i < 4; ++i) {
        int idx = tid + i * 256;
        int r  = idx >> 4;
        int c  = (idx & 15) * 4;
        const float4 v = *(const float4*)(ine + (size_t)(k0 + r) * N + n0 + c);
        tile[r][c + 0] = (short)f2bf(v.x);
        tile[r][c + 1] = (short)f2bf(v.y);
        tile[r][c + 2] = (short)f2bf(v.z);
        tile[r][c + 3] = (short)f2bf(v.w);
    }
    __syncthreads();
    #pragma unroll
    for (int i = 0; i < 4; ++i) {
        int idx = tid + i * 256;
        int n  = idx >> 4;
        int k  = (idx & 15) * 4;
        short4 s;
        s.x = tile[k + 0][n];
        s.y = tile[k + 1][n];
        s.z = tile[k + 2][n];
        s.w = tile[k + 3][n];
        *(short4*)(oute + (size_t)(n0 + n) * K + k0 + k) = s;
    }
}

// ---------------- pure-bf16 GEMM body (m97 structure), shared by gemm1/gemm2
// A [M,K] bf16 row-major, B [N,K] bf16 row-major (pre-transposed), 128x128 tile.
#define GEMM_PROLOG(Kdim)                                                      \
    __shared__ short As[128 * 32];                                             \
    __shared__ short Bs[128 * 32];                                             \
    const int tid  = threadIdx.x;                                              \
    const int lane = tid & 63;                                                 \
    const int wave = tid >> 6;                                                 \
    const int wm = (wave >> 1) * 64;                                           \
    const int wn = (wave &  1) * 64;                                           \
    const int lr = lane & 15;                                                  \
    const int lq = lane >> 4;                                                  \
    f32x4 acc[4][4] = {};                                                      \
    for (int k0 = 0; k0 < (Kdim); k0 += BK) {                                  \
        _Pragma("unroll")                                                      \
        for (int i = 0; i < 2; ++i) {                                          \
            int idx = tid + i * 256;                                           \
            int row = idx >> 2;                                                \
            int col = (idx & 3) * 8;                                           \
            gload_lds16(Ae + (size_t)(m0 + row) * (Kdim) + k0 + col,           \
                        As + (i * 256 + wave * 64) * 8);                       \
            gload_lds16(Be + (size_t)(n0 + row) * (Kdim) + k0 + col,           \
                        Bs + (i * 256 + wave * 64) * 8);                       \
        }                                                                      \
        __syncthreads();                                                       \
        bf16x8 a[4], b[4];                                                     \
        _Pragma("unroll")                                                      \
        for (int i = 0; i < 4; ++i)                                            \
            a[i] = *(const bf16x8*)(&As[(wm + i * 16 + lr) * 32 + lq * 8]);    \
        _Pragma("unroll")                                                      \
        for (int i = 0; i < 4; ++i)                                            \
            b[i] = *(const bf16x8*)(&Bs[(wn + i * 16 + lr) * 32 + lq * 8]);    \
        _Pragma("unroll")                                                      \
        for (int mi = 0; mi < 4; ++mi)                                         \
            _Pragma("unroll")                                                  \
            for (int ni = 0; ni < 4; ++ni)                                     \
                acc[mi][ni] = __builtin_amdgcn_mfma_f32_16x16x32_bf16(         \
                    a[mi], b[ni], acc[mi][ni], 0, 0, 0);                       \
        __syncthreads();                                                       \
    }

// GEMM1: H = gelu_erf(Xb @ W1t^T), Xb bf16 [M,DH], W1t bf16 [DI,DH], H bf16 [M,DI]
__global__ __launch_bounds__(256, 2)
void gemm1_bf16(const unsigned short* __restrict__ Xb,
                const unsigned short* __restrict__ W1t,
                unsigned short* __restrict__ H)
{
    const int e  = blockIdx.z;
    const int m0 = blockIdx.y * 128;
    const int n0 = blockIdx.x * 128;
    const unsigned short* Ae = Xb  + (size_t)e * MM * DH;
    const unsigned short* Be = W1t + (size_t)e * DI * DH;
    unsigned short* He = H + (size_t)e * MM * DI;

    GEMM_PROLOG(DH)

    #pragma unroll
    for (int mi = 0; mi < 4; ++mi) {
        #pragma unroll
        for (int ni = 0; ni < 4; ++ni) {
            const int col = n0 + wn + ni * 16 + lr;
            #pragma unroll
            for (int r = 0; r < 4; ++r) {
                const int row = m0 + wm + mi * 16 + lq * 4 + r;
                float v = acc[mi][ni][r];
                float g = 0.5f * v * (1.0f + erff(v * 0.70710678118654752f));
                He[(size_t)row * DI + col] = f2bf(g);
            }
        }
    }
}

// GEMM2: O = H @ W2t^T, H bf16 [M,DI], W2t bf16 [DH,DI], O fp32 [M,DH]
__global__ __launch_bounds__(256, 2)
void gemm2_bf16(const unsigned short* __restrict__ H,
                const unsigned short* __restrict__ W2t,
                float* __restrict__ O)
{
    const int e  = blockIdx.z;
    const int m0 = blockIdx.y * 128;
    const int n0 = blockIdx.x * 128;
    const unsigned short* Ae = H   + (size_t)e * MM * DI;
    const unsigned short* Be = W2t + (size_t)e * DH * DI;
    float* Oe = O + (size_t)e * MM * DH;

    GEMM_PROLOG(DI)

    #pragma unroll
    for (int mi = 0; mi < 4; ++mi) {
        #pragma unroll
        for (int ni = 0; ni < 4; ++ni) {
            const int col = n0 + wn + ni * 16 + lr;
            #pragma unroll
            for (int r = 0; r < 4; ++r) {
                const int row = m0 + wm + mi * 16 + lq * 4 + r;
                Oe[(size_t)row * DH + col] = acc[mi][ni][r];
            }
        }
    }
}

// ---------------- mid-tier gemm1 (fp32 X manually staged) — round-2 version
__global__ __launch_bounds__(256, 2)
void gemm1_mixed(const float* __restrict__ X, const unsigned short* __restrict__ W1t,
                 unsigned short* __restrict__ H)
{
    __shared__ short As[128 * LDA];
    __shared__ short Bs[128 * 32];
    const int e  = blockIdx.z;
    const int m0 = blockIdx.y * 128;
    const int n0 = blockIdx.x * 128;
    const float* Xe = X + (size_t)e * MM * DH;
    const unsigned short* Bt = W1t + (size_t)e * DI * DH;
    unsigned short* He = H + (size_t)e * MM * DI;
    const int tid  = threadIdx.x;
    const int lane = tid & 63;
    const int wave = tid >> 6;
    const int wm = (wave >> 1) * 64;
    const int wn = (wave &  1) * 64;
    const int lr = lane & 15;
    const int lq = lane >> 4;
    f32x4 acc[4][4] = {};
    for (int k0 = 0; k0 < DH; k0 += BK) {
        #pragma unroll
        for (int i = 0; i < 2; ++i) {
            int idx  = tid + i * 256;
            gload_lds16(Bt + (size_t)(n0 + (idx >> 2)) * DH + k0 + (idx & 3) * 8,
                        Bs + (i * 256 + wave * 64) * 8);
        }
        #pragma unroll
        for (int i = 0; i < 4; ++i) {
            int idx = tid + i * 256;
            int row = idx >> 3;
            int col = (idx & 7) * 4;
            const float4 v = *(const float4*)(Xe + (size_t)(m0 + row) * DH + k0 + col);
            short4 s;
            s.x = (short)f2bf(v.x); s.y = (short)f2bf(v.y);
            s.z = (short)f2bf(v.z); s.w = (short)f2bf(v.w);
            *(short4*)(&As[row * LDA + col]) = s;
        }
        __syncthreads();
        bf16x8 a[4], b[4];
        #pragma unroll
        for (int i = 0; i < 4; ++i)
            a[i] = *(const bf16x8*)(&As[(wm + i * 16 + lr) * LDA + lq * 8]);
        #pragma unroll
        for (int i = 0; i < 4; ++i)
            b[i] = *(const bf16x8*)(&Bs[(wn + i * 16 + lr) * 32 + lq * 8]);
        #pragma unroll
        for (int mi = 0; mi < 4; ++mi)
            #pragma unroll
            for (int ni = 0; ni < 4; ++ni)
                acc[mi][ni] = __builtin_amdgcn_mfma_f32_16x16x32_bf16(a[mi], b[ni], acc[mi][ni], 0, 0, 0);
        __syncthreads();
    }
    #pragma unroll
    for (int mi = 0; mi < 4; ++mi) {
        #pragma unroll
        for (int ni = 0; ni < 4; ++ni) {
            const int col = n0 + wn + ni * 16 + lr;
            #pragma unroll
            for (int r = 0; r < 4; ++r) {
                const int row = m0 + wm + mi * 16 + lq * 4 + r;
                float v = acc[mi][ni][r];
                float g = 0.5f * v * (1.0f + erff(v * 0.70710678118654752f));
                He[(size_t)row * DI + col] = f2bf(g);
            }
        }
    }
}

// ================= round-1 fallback (needs only 128MB ws) =================
__global__ __launch_bounds__(256, 2)
void fb_gemm1(const float* __restrict__ X, const float* __restrict__ W1,
              unsigned short* __restrict__ H)
{
    __shared__ short As[128 * LDA];
    __shared__ short Bs[128 * LDA];
    const int e  = blockIdx.z;
    const int m0 = blockIdx.y * 128;
    const int n0 = blockIdx.x * 128;
    const float* Xe  = X  + (size_t)e * MM * DH;
    const float* W1e = W1 + (size_t)e * DH * DI;
    unsigned short* He = H + (size_t)e * MM * DI;
    const int tid  = threadIdx.x;
    const int lane = tid & 63;
    const int wave = tid >> 6;
    const int wm = (wave >> 1) * 64;
    const int wn = (wave &  1) * 64;
    const int lr = lane & 15;
    const int lq = lane >> 4;
    f32x4 acc[4][4] = {};
    for (int k0 = 0; k0 < DH; k0 += BK) {
        #pragma unroll
        for (int i = 0; i < 4; ++i) {
            int idx = tid + i * 256;
            int row = idx >> 3;
            int col = (idx & 7) * 4;
            const float4 v = *(const float4*)(Xe + (size_t)(m0 + row) * DH + k0 + col);
            short4 s;
            s.x = (short)f2bf(v.x); s.y = (short)f2bf(v.y);
            s.z = (short)f2bf(v.z); s.w = (short)f2bf(v.w);
            *(short4*)(&As[row * LDA + col]) = s;
        }
        #pragma unroll
        for (int i = 0; i < 4; ++i) {
            int idx  = tid + i * 256;
            int krow = idx >> 5;
            int ncol = (idx & 31) * 4;
            const float4 v = *(const float4*)(W1e + (size_t)(k0 + krow) * DI + n0 + ncol);
            Bs[(ncol + 0) * LDA + krow] = (short)f2bf(v.x);
            Bs[(ncol + 1) * LDA + krow] = (short)f2bf(v.y);
            Bs[(ncol + 2) * LDA + krow] = (short)f2bf(v.z);
            Bs[(ncol + 3) * LDA + krow] = (short)f2bf(v.w);
        }
        __syncthreads();
        bf16x8 a[4], b[4];
        #pragma unroll
        for (int i = 0; i < 4; ++i)
            a[i] = *(const bf16x8*)(&As[(wm + i * 16 + lr) * LDA + lq * 8]);
        #pragma unroll
        for (int i = 0; i < 4; ++i)
            b[i] = *(const bf16x8*)(&Bs[(wn + i * 16 + lr) * LDA + lq * 8]);
        #pragma unroll
        for (int mi = 0; mi < 4; ++mi)
            #pragma unroll
            for (int ni = 0; ni < 4; ++ni)
                acc[mi][ni] = __builtin_amdgcn_mfma_f32_16x16x32_bf16(a[mi], b[ni], acc[mi][ni], 0, 0, 0);
        __syncthreads();
    }
    #pragma unroll
    for (int mi = 0; mi < 4; ++mi) {
        #pragma unroll
        for (int ni = 0; ni < 4; ++ni) {
            const int col = n0 + wn + ni * 16 + lr;
            #pragma unroll
            for (int r = 0; r < 4; ++r) {
                const int row = m0 + wm + mi * 16 + lq * 4 + r;
                float v = acc[mi][ni][r];
                float g = 0.5f * v * (1.0f + erff(v * 0.70710678118654752f));
                He[(size_t)row * DI + col] = f2bf(g);
            }
        }
    }
}

__global__ __launch_bounds__(256, 2)
void fb_gemm2(const unsigned short* __restrict__ H, const float* __restrict__ W2,
              float* __restrict__ O)
{
    __shared__ short As[128 * LDA];
    __shared__ short Bs[128 * LDA];
    const int e  = blockIdx.z;
    const int m0 = blockIdx.y * 128;
    const int n0 = blockIdx.x * 128;
    const unsigned short* He = H + (size_t)e * MM * DI;
    const float* W2e = W2 + (size_t)e * DI * DH;
    float* Oe = O + (size_t)e * MM * DH;
    const int tid  = threadIdx.x;
    const int lane = tid & 63;
    const int wave = tid >> 6;
    const int wm = (wave >> 1) * 64;
    const int wn = (wave &  1) * 64;
    const int lr = lane & 15;
    const int lq = lane >> 4;
    f32x4 acc[4][4] = {};
    for (int k0 = 0; k0 < DI; k0 += BK) {
        #pragma unroll
        for (int i = 0; i < 2; ++i) {
            int idx = tid + i * 256;
            int row = idx >> 2;
            int col = (idx & 3) * 8;
            bf16x8 v = *(const bf16x8*)(He + (size_t)(m0 + row) * DI + k0 + col);
            *(bf16x8*)(&As[row * LDA + col]) = v;
        }
        #pragma unroll
        for (int i = 0; i < 4; ++i) {
            int idx  = tid + i * 256;
            int krow = idx >> 5;
            int ncol = (idx & 31) * 4;
            const float4 v = *(const float4*)(W2e + (size_t)(k0 + krow) * DH + n0 + ncol);
            Bs[(ncol + 0) * LDA + krow] = (short)f2bf(v.x);
            Bs[(ncol + 1) * LDA + krow] = (short)f2bf(v.y);
            Bs[(ncol + 2) * LDA + krow] = (short)f2bf(v.z);
            Bs[(ncol + 3) * LDA + krow] = (short)f2bf(v.w);
        }
        __syncthreads();
        bf16x8 a[4], b[4];
        #pragma unroll
        for (int i = 0; i < 4; ++i)
            a[i] = *(const bf16x8*)(&As[(wm + i * 16 + lr) * LDA + lq * 8]);
        #pragma unroll
        for (int i = 0; i < 4; ++i)
            b[i] = *(const bf16x8*)(&Bs[(wn + i * 16 + lr) * LDA + lq * 8]);
        #pragma unroll
        for (int mi = 0; mi < 4; ++mi)
            #pragma unroll
            for (int ni = 0; ni < 4; ++ni)
                acc[mi][ni] = __builtin_amdgcn_mfma_f32_16x16x32_bf16(a[mi], b[ni], acc[mi][ni], 0, 0, 0);
        __syncthreads();
    }
    #pragma unroll
    for (int mi = 0; mi < 4; ++mi) {
        #pragma unroll
        for (int ni = 0; ni < 4; ++ni) {
            const int col = n0 + wn + ni * 16 + lr;
            #pragma unroll
            for (int r = 0; r < 4; ++r) {
                const int row = m0 + wm + mi * 16 + lq * 4 + r;
                Oe[(size_t)row * DH + col] = acc[mi][ni][r];
            }
        }
    }
}

extern "C" void kernel_launch(void* const* d_in, const int* in_sizes, int n_in,
                              void* d_out, int out_size, void* d_ws, size_t ws_size,
                              hipStream_t stream) {
    const float* x  = (const float*)d_in[0];
    const float* w1 = (const float*)d_in[1];
    const float* w2 = (const float*)d_in[2];
    float* out = (float*)d_out;

    const size_t WT_BYTES     = (size_t)NE * DH * DI * 2;   // 64 MB
    const size_t HIDDEN_BYTES = (size_t)NE * MM * DI * 2;   // 128 MB
    const size_t XB_BYTES     = (size_t)NE * MM * DH * 2;   // 32 MB

    dim3 blk(256);
    if (ws_size >= WT_BYTES + HIDDEN_BYTES + XB_BYTES) {
        unsigned short* wt     = (unsigned short*)d_ws;
        unsigned short* hidden = (unsigned short*)((char*)d_ws + WT_BYTES);
        unsigned short* xb     = (unsigned short*)((char*)d_ws + WT_BYTES + HIDDEN_BYTES);
        const long long nx = (long long)NE * MM * DH;
        convert_bf16<<<dim3((unsigned)(nx / (8 * 256))), blk, 0, stream>>>(x, xb, nx);
        transpose_bf16<<<dim3(DI / 64, DH / 64, NE), blk, 0, stream>>>(w1, wt, DH, DI);
        gemm1_bf16<<<dim3(DI / 128, MM / 128, NE), blk, 0, stream>>>(xb, wt, hidden);
        transpose_bf16<<<dim3(DH / 64, DI / 64, NE), blk, 0, stream>>>(w2, wt, DI, DH);
        gemm2_bf16<<<dim3(DH / 128, MM / 128, NE), blk, 0, stream>>>(hidden, wt, out);
    } else if (ws_size >= WT_BYTES + HIDDEN_BYTES) {
        unsigned short* wt     = (unsigned short*)d_ws;
        unsigned short* hidden = (unsigned short*)((char*)d_ws + WT_BYTES);
        transpose_bf16<<<dim3(DI / 64, DH / 64, NE), blk, 0, stream>>>(w1, wt, DH, DI);
        gemm1_mixed<<<dim3(DI / 128, MM / 128, NE), blk, 0, stream>>>(x, wt, hidden);
        transpose_bf16<<<dim3(DH / 64, DI / 64, NE), blk, 0, stream>>>(w2, wt, DI, DH);
        gemm2_bf16<<<dim3(DH / 128, MM / 128, NE), blk, 0, stream>>>(hidden, wt, out);
    } else {
        unsigned short* hidden = (unsigned short*)d_ws;
        fb_gemm1<<<dim3(DI / 128, MM / 128, NE), blk, 0, stream>>>(x, w1, hidden);
        fb_gemm2<<<dim3(DH / 128, MM / 128, NE), blk, 0, stream>>>(hidden, w2, out);
    }
}